// Round 15
// baseline (254.981 us; speedup 1.0000x reference)
//
#include <hip/hip_runtime.h>
#include <hip/hip_bf16.h>
#include <stdint.h>

#define BB 2
#define SS 2048
#define HQ 32
#define HKV 8
#define DD 128
#define WIN 512

typedef __bf16 bf16x8 __attribute__((ext_vector_type(8)));
typedef float f32x16 __attribute__((ext_vector_type(16)));

__device__ __forceinline__ bf16x8 cvt8(float4 a, float4 b, float s) {
  bf16x8 r;
  r[0] = (__bf16)(a.x * s); r[1] = (__bf16)(a.y * s);
  r[2] = (__bf16)(a.z * s); r[3] = (__bf16)(a.w * s);
  r[4] = (__bf16)(b.x * s); r[5] = (__bf16)(b.y * s);
  r[6] = (__bf16)(b.z * s); r[7] = (__bf16)(b.w * s);
  return r;
}

__device__ __forceinline__ uint32_t pk2(float lo, float hi) {
  uint32_t w;
  asm("v_cvt_pk_bf16_f32 %0, %1, %2" : "=v"(w) : "v"(lo), "v"(hi));
  return w;
}

__device__ __forceinline__ unsigned short bfu(float x) {
  union { __bf16 b; unsigned short u; } c; c.b = (__bf16)x; return c.u;
}

#define SWZ(r) ((((r) ^ ((r) >> 3)) & 7) << 4)

// ---- shared prologue macro-free helpers (kept identical across variants) ----

// ============ FULL kernel (R12, verified 94us): bf16-prepped K/V, LDS dbuf ============
__global__ __launch_bounds__(512, 2) void attn_kernel(
    const float* __restrict__ qg, const float* __restrict__ sinkg,
    float* __restrict__ outg,
    const unsigned short* __restrict__ kbg, const unsigned short* __restrict__ vtg)
{
  const int col = (blockIdx.x & 7) + 8 * ((blockIdx.x >> 3) & 1);
  const int rank = blockIdx.x >> 4;
  const int qtile = rank < 24 ? rank + 8 : 31 - rank;
  const int hkv = col & 7, b = col >> 3;
  const int qb = qtile * 64;
  const int tid = threadIdx.x;
  const int wave = tid >> 6, lane = tid & 63;
  const int c5 = lane & 31, hi = lane >> 5;
  const int hq = (hkv << 2) + (wave >> 1);
  const int qw = qb + (wave & 1) * 32;
  const int qrow = qw + c5;

  __shared__ __align__(16) __bf16 Kl[2][64 * 128];
  __shared__ __align__(16) __bf16 Vt[2][128 * 64];

  const float LOG2E = 1.4426950408889634f;
  const float scale = 0.08838834764831845f * LOG2E;
  const float THR = 12.0f;

  bf16x8 qf[8];
  {
    const float* qp = qg + (((size_t)b * SS + qrow) * HQ + hq) * DD + hi * 8;
    #pragma unroll
    for (int ch = 0; ch < 8; ++ch) {
      float4 a = *(const float4*)(qp + ch * 16);
      float4 a2 = *(const float4*)(qp + ch * 16 + 4);
      qf[ch] = cvt8(a, a2, scale);
    }
  }
  const float sk = sinkg[hq] * LOG2E;

  float mm = -1e30f, ll = 0.f;
  f32x16 acc[4];
  #pragma unroll
  for (int d = 0; d < 4; ++d)
    #pragma unroll
    for (int r = 0; r < 16; ++r) acc[d][r] = 0.f;

  const int t0 = (qb > (WIN - 1) ? (qb - (WIN - 1)) : 0) >> 6;
  const int t1 = (qb + 63) >> 6;

  const char* kcol = (const char*)kbg + (size_t)(b * HKV + hkv) * (SS * DD * 2);
  const char* vcol = (const char*)vtg + (size_t)(b * HKV + hkv) * (SS * DD * 2);
  const int p0 = tid * 32;
  const int kr = p0 >> 8, kx = p0 & 255;
  const int vrw = p0 >> 7, vx = p0 & 127;
  const int kd0 = kr * 256 + (kx ^ SWZ(kr)), kd1 = kr * 256 + ((kx + 16) ^ SWZ(kr));
  const int vd0 = vrw * 128 + (vx ^ SWZ(vrw)), vd1 = vrw * 128 + ((vx + 16) ^ SWZ(vrw));

  uint4 ksA, ksB, vsA, vsB;
  auto issue = [&](int t) {
    const char* kt = kcol + (size_t)t * 16384;
    const char* vt = vcol + (size_t)t * 16384;
    ksA = *(const uint4*)(kt + p0); ksB = *(const uint4*)(kt + p0 + 16);
    vsA = *(const uint4*)(vt + p0); vsB = *(const uint4*)(vt + p0 + 16);
  };
  auto commit = [&](int buf) {
    char* kb_ = (char*)&Kl[buf][0]; char* vb_ = (char*)&Vt[buf][0];
    *(uint4*)(kb_ + kd0) = ksA; *(uint4*)(kb_ + kd1) = ksB;
    *(uint4*)(vb_ + vd0) = vsA; *(uint4*)(vb_ + vd1) = vsB;
  };

  issue(t0);
  commit(0);
  __syncthreads();
  int cur = 0;

  const int swA = SWZ(c5);
  const int swB = swA ^ 0x40;

  for (int t = t0; t <= t1; ++t) {
    if (t < t1) issue(t + 1);
    const int kb = t << 6;

    if (kb <= qw + 31 && kb + 63 >= qw - (WIN - 1)) {
      const char* Ksc = (const char*)&Kl[cur][0];
      const char* Vsc = (const char*)&Vt[cur][0];

      f32x16 s0, s1;
      #pragma unroll
      for (int r = 0; r < 16; ++r) { s0[r] = 0.f; s1[r] = 0.f; }
      __builtin_amdgcn_s_setprio(1);
      #pragma unroll
      for (int ch = 0; ch < 8; ++ch) {
        const int colb = ch * 32 + hi * 16;
        bf16x8 a0 = *(const bf16x8*)(Ksc + c5 * 256 + (colb ^ swA));
        bf16x8 a1 = *(const bf16x8*)(Ksc + (32 + c5) * 256 + (colb ^ swB));
        s0 = __builtin_amdgcn_mfma_f32_32x32x16_bf16(a0, qf[ch], s0, 0, 0, 0);
        s1 = __builtin_amdgcn_mfma_f32_32x32x16_bf16(a1, qf[ch], s1, 0, 0, 0);
      }
      __builtin_amdgcn_s_setprio(0);

      const bool noMask = (kb + 63 <= qw) && (kb >= qw - (WIN - 32));

      if (!noMask) {
        #pragma unroll
        for (int r = 0; r < 16; ++r) {
          const int lr = (r & 3) + 8 * (r >> 2) + 4 * hi;
          const int kv0 = kb + lr, kv1 = kv0 + 32;
          const bool ok0 = (kv0 <= qrow) && (qrow - kv0 < WIN);
          const bool ok1 = (kv1 <= qrow) && (qrow - kv1 < WIN);
          s0[r] = ok0 ? s0[r] : -1e30f;
          s1[r] = ok1 ? s1[r] : -1e30f;
        }
      }
      float tmax = s0[0];
      #pragma unroll
      for (int r = 1; r < 16; ++r) tmax = fmaxf(tmax, s0[r]);
      #pragma unroll
      for (int r = 0; r < 16; ++r) tmax = fmaxf(tmax, s1[r]);
      tmax = fmaxf(tmax, __shfl_xor(tmax, 32));

      const bool resc = __any(tmax > mm + THR);
      const float mnew = resc ? fmaxf(mm, tmax) : mm;
      float tsum = 0.f;
      if (noMask) {
        #pragma unroll
        for (int r = 0; r < 16; ++r) {
          s0[r] = exp2f(s0[r] - mnew); tsum += s0[r];
          s1[r] = exp2f(s1[r] - mnew); tsum += s1[r];
        }
      } else {
        #pragma unroll
        for (int r = 0; r < 16; ++r) {
          s0[r] = (s0[r] > -9e29f) ? exp2f(s0[r] - mnew) : 0.f; tsum += s0[r];
          s1[r] = (s1[r] > -9e29f) ? exp2f(s1[r] - mnew) : 0.f; tsum += s1[r];
        }
      }
      tsum += __shfl_xor(tsum, 32);

      if (resc) {
        const float scl = exp2f(mm - mnew);
        ll = ll * scl + tsum;
        #pragma unroll
        for (int d = 0; d < 4; ++d)
          #pragma unroll
          for (int r = 0; r < 16; ++r) acc[d][r] *= scl;
        mm = mnew;
      } else {
        ll += tsum;
      }

      bf16x8 pb[4];
      #pragma unroll
      for (int kvq = 0; kvq < 4; ++kvq) {
        const int bq = (kvq & 1) * 8;
        float e0, e1, e2, e3, e4, e5, e6, e7;
        if (kvq & 2) {
          e0 = s1[bq+0]; e1 = s1[bq+1]; e2 = s1[bq+2]; e3 = s1[bq+3];
          e4 = s1[bq+4]; e5 = s1[bq+5]; e6 = s1[bq+6]; e7 = s1[bq+7];
        } else {
          e0 = s0[bq+0]; e1 = s0[bq+1]; e2 = s0[bq+2]; e3 = s0[bq+3];
          e4 = s0[bq+4]; e5 = s0[bq+5]; e6 = s0[bq+6]; e7 = s0[bq+7];
        }
        const uint32_t A0 = pk2(e0, e1), A1 = pk2(e2, e3);
        const uint32_t B0 = pk2(e4, e5), B1 = pk2(e6, e7);
        const uint32_t XA0 = __shfl_xor(A0, 32), XA1 = __shfl_xor(A1, 32);
        const uint32_t XB0 = __shfl_xor(B0, 32), XB1 = __shfl_xor(B1, 32);
        union { uint4 u; bf16x8 v; } cvu;
        cvu.u.x = hi ? XB0 : A0;
        cvu.u.y = hi ? XB1 : A1;
        cvu.u.z = hi ? B0 : XA0;
        cvu.u.w = hi ? B1 : XA1;
        pb[kvq] = cvu.v;
      }

      __builtin_amdgcn_s_setprio(1);
      #pragma unroll
      for (int d = 0; d < 4; ++d) {
        const int rowb = (d * 32 + c5) * 128;
        const int swV = swA ^ ((d & 1) << 6);
        #pragma unroll
        for (int kvq = 0; kvq < 4; ++kvq) {
          bf16x8 va = *(const bf16x8*)(Vsc + rowb + ((kvq * 32 + hi * 16) ^ swV));
          acc[d] = __builtin_amdgcn_mfma_f32_32x32x16_bf16(va, pb[kvq], acc[d], 0, 0, 0);
        }
      }
      __builtin_amdgcn_s_setprio(0);
    }

    if (t < t1) {
      commit(cur ^ 1);
      __syncthreads();
      cur ^= 1;
    }
  }

  {
    const float Mf = fmaxf(mm, sk);
    const float ex = exp2f(mm - Mf);
    const float denom = ll * ex + exp2f(sk - Mf);
    const float fac = ex / denom;
    float* orow = outg + (((size_t)b * SS + qrow) * HQ + hq) * DD;
    #pragma unroll
    for (int d = 0; d < 4; ++d) {
      #pragma unroll
      for (int q4 = 0; q4 < 4; ++q4) {
        float4 o;
        o.x = acc[d][q4 * 4 + 0] * fac;
        o.y = acc[d][q4 * 4 + 1] * fac;
        o.z = acc[d][q4 * 4 + 2] * fac;
        o.w = acc[d][q4 * 4 + 3] * fac;
        *(float4*)(orow + d * 32 + q4 * 8 + 4 * hi) = o;
      }
    }
  }
}

// ============ ABLATION V1: staging + dbuf + barriers + all LDS frag reads ============
__global__ __launch_bounds__(512, 2) void ab_loads(
    const float* __restrict__ qg,
    const unsigned short* __restrict__ kbg, const unsigned short* __restrict__ vtg,
    float* __restrict__ dump)
{
  const int col = (blockIdx.x & 7) + 8 * ((blockIdx.x >> 3) & 1);
  const int rank = blockIdx.x >> 4;
  const int qtile = rank < 24 ? rank + 8 : 31 - rank;
  const int hkv = col & 7, b = col >> 3;
  const int qb = qtile * 64;
  const int tid = threadIdx.x;
  const int wave = tid >> 6, lane = tid & 63;
  const int c5 = lane & 31, hi = lane >> 5;
  const int hq = (hkv << 2) + (wave >> 1);
  const int qw = qb + (wave & 1) * 32;
  const int qrow = qw + c5;

  __shared__ __align__(16) __bf16 Kl[2][64 * 128];
  __shared__ __align__(16) __bf16 Vt[2][128 * 64];

  const float scale = 0.12754875f;
  bf16x8 qf[8];
  {
    const float* qp = qg + (((size_t)b * SS + qrow) * HQ + hq) * DD + hi * 8;
    #pragma unroll
    for (int ch = 0; ch < 8; ++ch) {
      float4 a = *(const float4*)(qp + ch * 16);
      float4 a2 = *(const float4*)(qp + ch * 16 + 4);
      qf[ch] = cvt8(a, a2, scale);
    }
  }

  f32x16 acc[4];
  #pragma unroll
  for (int d = 0; d < 4; ++d)
    #pragma unroll
    for (int r = 0; r < 16; ++r) acc[d][r] = 0.f;
  #pragma unroll
  for (int ch = 0; ch < 8; ++ch) acc[ch & 3][ch >> 1] += (float)qf[ch][0];

  const int t0 = (qb > (WIN - 1) ? (qb - (WIN - 1)) : 0) >> 6;
  const int t1 = (qb + 63) >> 6;

  const char* kcol = (const char*)kbg + (size_t)(b * HKV + hkv) * (SS * DD * 2);
  const char* vcol = (const char*)vtg + (size_t)(b * HKV + hkv) * (SS * DD * 2);
  const int p0 = tid * 32;
  const int kr = p0 >> 8, kx = p0 & 255;
  const int vrw = p0 >> 7, vx = p0 & 127;
  const int kd0 = kr * 256 + (kx ^ SWZ(kr)), kd1 = kr * 256 + ((kx + 16) ^ SWZ(kr));
  const int vd0 = vrw * 128 + (vx ^ SWZ(vrw)), vd1 = vrw * 128 + ((vx + 16) ^ SWZ(vrw));

  uint4 ksA, ksB, vsA, vsB;
  auto issue = [&](int t) {
    const char* kt = kcol + (size_t)t * 16384;
    const char* vt = vcol + (size_t)t * 16384;
    ksA = *(const uint4*)(kt + p0); ksB = *(const uint4*)(kt + p0 + 16);
    vsA = *(const uint4*)(vt + p0); vsB = *(const uint4*)(vt + p0 + 16);
  };
  auto commit = [&](int buf) {
    char* kb_ = (char*)&Kl[buf][0]; char* vb_ = (char*)&Vt[buf][0];
    *(uint4*)(kb_ + kd0) = ksA; *(uint4*)(kb_ + kd1) = ksB;
    *(uint4*)(vb_ + vd0) = vsA; *(uint4*)(vb_ + vd1) = vsB;
  };

  issue(t0);
  commit(0);
  __syncthreads();
  int cur = 0;

  const int swA = SWZ(c5);
  const int swB = swA ^ 0x40;

  for (int t = t0; t <= t1; ++t) {
    if (t < t1) issue(t + 1);
    const int kb = t << 6;

    if (kb <= qw + 31 && kb + 63 >= qw - (WIN - 1)) {
      const char* Ksc = (const char*)&Kl[cur][0];
      const char* Vsc = (const char*)&Vt[cur][0];
      uint32_t fx = 0, fy = 0, fz = 0, fw = 0;
      #pragma unroll
      for (int ch = 0; ch < 8; ++ch) {
        const int colb = ch * 32 + hi * 16;
        uint4 a0 = *(const uint4*)(Ksc + c5 * 256 + (colb ^ swA));
        uint4 a1 = *(const uint4*)(Ksc + (32 + c5) * 256 + (colb ^ swB));
        fx ^= a0.x ^ a1.x; fy ^= a0.y ^ a1.y; fz ^= a0.z ^ a1.z; fw ^= a0.w ^ a1.w;
      }
      #pragma unroll
      for (int d = 0; d < 4; ++d) {
        const int rowb = (d * 32 + c5) * 128;
        const int swV = swA ^ ((d & 1) << 6);
        #pragma unroll
        for (int kvq = 0; kvq < 4; ++kvq) {
          uint4 va = *(const uint4*)(Vsc + rowb + ((kvq * 32 + hi * 16) ^ swV));
          fx ^= va.x; fy ^= va.y; fz ^= va.z; fw ^= va.w;
        }
      }
      const int sl = t & 3;
      acc[sl][t & 15] = __uint_as_float(
          __float_as_uint(acc[sl][t & 15]) ^ fx ^ fy ^ fz ^ fw);
    }

    if (t < t1) {
      commit(cur ^ 1);
      __syncthreads();
      cur ^= 1;
    }
  }

  float* dp = dump + ((size_t)blockIdx.x * 512 + tid) * 4;
  #pragma unroll
  for (int d = 0; d < 4; ++d) {
    float s = 0.f;
    #pragma unroll
    for (int r = 0; r < 16; ++r) s += acc[d][r];
    dp[d] = s;
  }
}

// ============ ABLATION V2: V1 + real QK^T MFMAs (no softmax, no PV) ============
__global__ __launch_bounds__(512, 2) void ab_qk(
    const float* __restrict__ qg,
    const unsigned short* __restrict__ kbg, const unsigned short* __restrict__ vtg,
    float* __restrict__ dump)
{
  const int col = (blockIdx.x & 7) + 8 * ((blockIdx.x >> 3) & 1);
  const int rank = blockIdx.x >> 4;
  const int qtile = rank < 24 ? rank + 8 : 31 - rank;
  const int hkv = col & 7, b = col >> 3;
  const int qb = qtile * 64;
  const int tid = threadIdx.x;
  const int wave = tid >> 6, lane = tid & 63;
  const int c5 = lane & 31, hi = lane >> 5;
  const int hq = (hkv << 2) + (wave >> 1);
  const int qw = qb + (wave & 1) * 32;
  const int qrow = qw + c5;

  __shared__ __align__(16) __bf16 Kl[2][64 * 128];
  __shared__ __align__(16) __bf16 Vt[2][128 * 64];

  const float scale = 0.12754875f;
  bf16x8 qf[8];
  {
    const float* qp = qg + (((size_t)b * SS + qrow) * HQ + hq) * DD + hi * 8;
    #pragma unroll
    for (int ch = 0; ch < 8; ++ch) {
      float4 a = *(const float4*)(qp + ch * 16);
      float4 a2 = *(const float4*)(qp + ch * 16 + 4);
      qf[ch] = cvt8(a, a2, scale);
    }
  }

  f32x16 acc[4];
  #pragma unroll
  for (int d = 0; d < 4; ++d)
    #pragma unroll
    for (int r = 0; r < 16; ++r) acc[d][r] = 0.f;

  const int t0 = (qb > (WIN - 1) ? (qb - (WIN - 1)) : 0) >> 6;
  const int t1 = (qb + 63) >> 6;

  const char* kcol = (const char*)kbg + (size_t)(b * HKV + hkv) * (SS * DD * 2);
  const char* vcol = (const char*)vtg + (size_t)(b * HKV + hkv) * (SS * DD * 2);
  const int p0 = tid * 32;
  const int kr = p0 >> 8, kx = p0 & 255;
  const int vrw = p0 >> 7, vx = p0 & 127;
  const int kd0 = kr * 256 + (kx ^ SWZ(kr)), kd1 = kr * 256 + ((kx + 16) ^ SWZ(kr));
  const int vd0 = vrw * 128 + (vx ^ SWZ(vrw)), vd1 = vrw * 128 + ((vx + 16) ^ SWZ(vrw));

  uint4 ksA, ksB, vsA, vsB;
  auto issue = [&](int t) {
    const char* kt = kcol + (size_t)t * 16384;
    const char* vt = vcol + (size_t)t * 16384;
    ksA = *(const uint4*)(kt + p0); ksB = *(const uint4*)(kt + p0 + 16);
    vsA = *(const uint4*)(vt + p0); vsB = *(const uint4*)(vt + p0 + 16);
  };
  auto commit = [&](int buf) {
    char* kb_ = (char*)&Kl[buf][0]; char* vb_ = (char*)&Vt[buf][0];
    *(uint4*)(kb_ + kd0) = ksA; *(uint4*)(kb_ + kd1) = ksB;
    *(uint4*)(vb_ + vd0) = vsA; *(uint4*)(vb_ + vd1) = vsB;
  };

  issue(t0);
  commit(0);
  __syncthreads();
  int cur = 0;

  const int swA = SWZ(c5);
  const int swB = swA ^ 0x40;

  for (int t = t0; t <= t1; ++t) {
    if (t < t1) issue(t + 1);
    const int kb = t << 6;

    if (kb <= qw + 31 && kb + 63 >= qw - (WIN - 1)) {
      const char* Ksc = (const char*)&Kl[cur][0];
      const char* Vsc = (const char*)&Vt[cur][0];

      f32x16 s0, s1;
      #pragma unroll
      for (int r = 0; r < 16; ++r) { s0[r] = 0.f; s1[r] = 0.f; }
      __builtin_amdgcn_s_setprio(1);
      #pragma unroll
      for (int ch = 0; ch < 8; ++ch) {
        const int colb = ch * 32 + hi * 16;
        bf16x8 a0 = *(const bf16x8*)(Ksc + c5 * 256 + (colb ^ swA));
        bf16x8 a1 = *(const bf16x8*)(Ksc + (32 + c5) * 256 + (colb ^ swB));
        s0 = __builtin_amdgcn_mfma_f32_32x32x16_bf16(a0, qf[ch], s0, 0, 0, 0);
        s1 = __builtin_amdgcn_mfma_f32_32x32x16_bf16(a1, qf[ch], s1, 0, 0, 0);
      }
      __builtin_amdgcn_s_setprio(0);

      // keep V memory traffic (fold bits)
      uint32_t fx = 0, fy = 0, fz = 0, fw = 0;
      #pragma unroll
      for (int d = 0; d < 4; ++d) {
        const int rowb = (d * 32 + c5) * 128;
        const int swV = swA ^ ((d & 1) << 6);
        #pragma unroll
        for (int kvq = 0; kvq < 4; ++kvq) {
          uint4 va = *(const uint4*)(Vsc + rowb + ((kvq * 32 + hi * 16) ^ swV));
          fx ^= va.x; fy ^= va.y; fz ^= va.z; fw ^= va.w;
        }
      }
      #pragma unroll
      for (int r = 0; r < 16; ++r) { acc[0][r] += s0[r]; acc[1][r] += s1[r]; }
      acc[2][t & 15] = __uint_as_float(
          __float_as_uint(acc[2][t & 15]) ^ fx ^ fy ^ fz ^ fw);
    }

    if (t < t1) {
      commit(cur ^ 1);
      __syncthreads();
      cur ^= 1;
    }
  }

  float* dp = dump + ((size_t)blockIdx.x * 512 + tid) * 4;
  #pragma unroll
  for (int d = 0; d < 4; ++d) {
    float s = 0.f;
    #pragma unroll
    for (int r = 0; r < 16; ++r) s += acc[d][r];
    dp[d] = s;
  }
}

// ============ ABLATION V3: V2(K path) + full softmax + P-exchange (no V reads, no PV) ============
__global__ __launch_bounds__(512, 2) void ab_sm(
    const float* __restrict__ qg,
    const unsigned short* __restrict__ kbg, const unsigned short* __restrict__ vtg,
    float* __restrict__ dump)
{
  const int col = (blockIdx.x & 7) + 8 * ((blockIdx.x >> 3) & 1);
  const int rank = blockIdx.x >> 4;
  const int qtile = rank < 24 ? rank + 8 : 31 - rank;
  const int hkv = col & 7, b = col >> 3;
  const int qb = qtile * 64;
  const int tid = threadIdx.x;
  const int wave = tid >> 6, lane = tid & 63;
  const int c5 = lane & 31, hi = lane >> 5;
  const int hq = (hkv << 2) + (wave >> 1);
  const int qw = qb + (wave & 1) * 32;
  const int qrow = qw + c5;

  __shared__ __align__(16) __bf16 Kl[2][64 * 128];
  __shared__ __align__(16) __bf16 Vt[2][128 * 64];

  const float LOG2E = 1.4426950408889634f;
  const float scale = 0.08838834764831845f * LOG2E;
  const float THR = 12.0f;

  bf16x8 qf[8];
  {
    const float* qp = qg + (((size_t)b * SS + qrow) * HQ + hq) * DD + hi * 8;
    #pragma unroll
    for (int ch = 0; ch < 8; ++ch) {
      float4 a = *(const float4*)(qp + ch * 16);
      float4 a2 = *(const float4*)(qp + ch * 16 + 4);
      qf[ch] = cvt8(a, a2, scale);
    }
  }

  float mm = -1e30f, ll = 0.f;
  f32x16 acc[4];
  #pragma unroll
  for (int d = 0; d < 4; ++d)
    #pragma unroll
    for (int r = 0; r < 16; ++r) acc[d][r] = 0.f;

  const int t0 = (qb > (WIN - 1) ? (qb - (WIN - 1)) : 0) >> 6;
  const int t1 = (qb + 63) >> 6;

  const char* kcol = (const char*)kbg + (size_t)(b * HKV + hkv) * (SS * DD * 2);
  const char* vcol = (const char*)vtg + (size_t)(b * HKV + hkv) * (SS * DD * 2);
  const int p0 = tid * 32;
  const int kr = p0 >> 8, kx = p0 & 255;
  const int vrw = p0 >> 7, vx = p0 & 127;
  const int kd0 = kr * 256 + (kx ^ SWZ(kr)), kd1 = kr * 256 + ((kx + 16) ^ SWZ(kr));
  const int vd0 = vrw * 128 + (vx ^ SWZ(vrw)), vd1 = vrw * 128 + ((vx + 16) ^ SWZ(vrw));

  uint4 ksA, ksB, vsA, vsB;
  auto issue = [&](int t) {
    const char* kt = kcol + (size_t)t * 16384;
    const char* vt = vcol + (size_t)t * 16384;
    ksA = *(const uint4*)(kt + p0); ksB = *(const uint4*)(kt + p0 + 16);
    vsA = *(const uint4*)(vt + p0); vsB = *(const uint4*)(vt + p0 + 16);
  };
  auto commit = [&](int buf) {
    char* kb_ = (char*)&Kl[buf][0]; char* vb_ = (char*)&Vt[buf][0];
    *(uint4*)(kb_ + kd0) = ksA; *(uint4*)(kb_ + kd1) = ksB;
    *(uint4*)(vb_ + vd0) = vsA; *(uint4*)(vb_ + vd1) = vsB;
  };

  issue(t0);
  commit(0);
  __syncthreads();
  int cur = 0;

  const int swA = SWZ(c5);
  const int swB = swA ^ 0x40;

  for (int t = t0; t <= t1; ++t) {
    if (t < t1) issue(t + 1);
    const int kb = t << 6;

    if (kb <= qw + 31 && kb + 63 >= qw - (WIN - 1)) {
      const char* Ksc = (const char*)&Kl[cur][0];

      f32x16 s0, s1;
      #pragma unroll
      for (int r = 0; r < 16; ++r) { s0[r] = 0.f; s1[r] = 0.f; }
      __builtin_amdgcn_s_setprio(1);
      #pragma unroll
      for (int ch = 0; ch < 8; ++ch) {
        const int colb = ch * 32 + hi * 16;
        bf16x8 a0 = *(const bf16x8*)(Ksc + c5 * 256 + (colb ^ swA));
        bf16x8 a1 = *(const bf16x8*)(Ksc + (32 + c5) * 256 + (colb ^ swB));
        s0 = __builtin_amdgcn_mfma_f32_32x32x16_bf16(a0, qf[ch], s0, 0, 0, 0);
        s1 = __builtin_amdgcn_mfma_f32_32x32x16_bf16(a1, qf[ch], s1, 0, 0, 0);
      }
      __builtin_amdgcn_s_setprio(0);

      const bool noMask = (kb + 63 <= qw) && (kb >= qw - (WIN - 32));
      if (!noMask) {
        #pragma unroll
        for (int r = 0; r < 16; ++r) {
          const int lr = (r & 3) + 8 * (r >> 2) + 4 * hi;
          const int kv0 = kb + lr, kv1 = kv0 + 32;
          const bool ok0 = (kv0 <= qrow) && (qrow - kv0 < WIN);
          const bool ok1 = (kv1 <= qrow) && (qrow - kv1 < WIN);
          s0[r] = ok0 ? s0[r] : -1e30f;
          s1[r] = ok1 ? s1[r] : -1e30f;
        }
      }
      float tmax = s0[0];
      #pragma unroll
      for (int r = 1; r < 16; ++r) tmax = fmaxf(tmax, s0[r]);
      #pragma unroll
      for (int r = 0; r < 16; ++r) tmax = fmaxf(tmax, s1[r]);
      tmax = fmaxf(tmax, __shfl_xor(tmax, 32));

      const bool resc = __any(tmax > mm + THR);
      const float mnew = resc ? fmaxf(mm, tmax) : mm;
      float tsum = 0.f;
      if (noMask) {
        #pragma unroll
        for (int r = 0; r < 16; ++r) {
          s0[r] = exp2f(s0[r] - mnew); tsum += s0[r];
          s1[r] = exp2f(s1[r] - mnew); tsum += s1[r];
        }
      } else {
        #pragma unroll
        for (int r = 0; r < 16; ++r) {
          s0[r] = (s0[r] > -9e29f) ? exp2f(s0[r] - mnew) : 0.f; tsum += s0[r];
          s1[r] = (s1[r] > -9e29f) ? exp2f(s1[r] - mnew) : 0.f; tsum += s1[r];
        }
      }
      tsum += __shfl_xor(tsum, 32);

      if (resc) {
        const float scl = exp2f(mm - mnew);
        ll = ll * scl + tsum;
        #pragma unroll
        for (int d = 0; d < 4; ++d)
          #pragma unroll
          for (int r = 0; r < 16; ++r) acc[d][r] *= scl;
        mm = mnew;
      } else {
        ll += tsum;
      }

      bf16x8 pb[4];
      #pragma unroll
      for (int kvq = 0; kvq < 4; ++kvq) {
        const int bq = (kvq & 1) * 8;
        float e0, e1, e2, e3, e4, e5, e6, e7;
        if (kvq & 2) {
          e0 = s1[bq+0]; e1 = s1[bq+1]; e2 = s1[bq+2]; e3 = s1[bq+3];
          e4 = s1[bq+4]; e5 = s1[bq+5]; e6 = s1[bq+6]; e7 = s1[bq+7];
        } else {
          e0 = s0[bq+0]; e1 = s0[bq+1]; e2 = s0[bq+2]; e3 = s0[bq+3];
          e4 = s0[bq+4]; e5 = s0[bq+5]; e6 = s0[bq+6]; e7 = s0[bq+7];
        }
        const uint32_t A0 = pk2(e0, e1), A1 = pk2(e2, e3);
        const uint32_t B0 = pk2(e4, e5), B1 = pk2(e6, e7);
        const uint32_t XA0 = __shfl_xor(A0, 32), XA1 = __shfl_xor(A1, 32);
        const uint32_t XB0 = __shfl_xor(B0, 32), XB1 = __shfl_xor(B1, 32);
        union { uint4 u; bf16x8 v; } cvu;
        cvu.u.x = hi ? XB0 : A0;
        cvu.u.y = hi ? XB1 : A1;
        cvu.u.z = hi ? B0 : XA0;
        cvu.u.w = hi ? B1 : XA1;
        pb[kvq] = cvu.v;
      }
      // keep pb alive via bit-fold
      uint32_t fx = 0;
      #pragma unroll
      for (int kvq = 0; kvq < 4; ++kvq) {
        union { bf16x8 v; uint4 u; } pu; pu.v = pb[kvq];
        fx ^= pu.u.x ^ pu.u.y ^ pu.u.z ^ pu.u.w;
      }
      acc[3][t & 15] = __uint_as_float(__float_as_uint(acc[3][t & 15]) ^ fx);
    }

    if (t < t1) {
      commit(cur ^ 1);
      __syncthreads();
      cur ^= 1;
    }
  }

  float* dp = dump + ((size_t)blockIdx.x * 512 + tid) * 4;
  #pragma unroll
  for (int d = 0; d < 4; ++d) {
    float s = 0.f;
    #pragma unroll
    for (int r = 0; r < 16; ++r) s += acc[d][r];
    dp[d] = s + mm + ll;
  }
}

// ============ prep: fp32 K/V -> bf16 Kb[col][s][d], Vt[col][tile][d][kv] ============
__global__ void prep_kv(const float* __restrict__ kg, const float* __restrict__ vg,
                        unsigned short* __restrict__ kb, unsigned short* __restrict__ vt) {
  const int bx = blockIdx.x;
  const int t = bx & 31, colx = bx >> 5;
  const int b = colx >> 3, hkv = colx & 7;
  const int kbrow = t * 64;
  if (blockIdx.y == 0) {
    #pragma unroll
    for (int i = 0; i < 8; ++i) {
      const int idx = i * 1024 + threadIdx.x * 4;
      const int r = idx >> 7, d = idx & 127;
      float4 v = *(const float4*)(kg + (((size_t)b * SS + kbrow + r) * HKV + hkv) * DD + d);
      ushort4 o = make_ushort4(bfu(v.x), bfu(v.y), bfu(v.z), bfu(v.w));
      *(ushort4*)(kb + ((size_t)colx * SS + kbrow + r) * DD + d) = o;
    }
  } else {
    __shared__ unsigned short Vl[64][132];
    #pragma unroll
    for (int i = 0; i < 8; ++i) {
      const int idx = i * 1024 + threadIdx.x * 4;
      const int kv = idx >> 7, d = idx & 127;
      float4 v = *(const float4*)(vg + (((size_t)b * SS + kbrow + kv) * HKV + hkv) * DD + d);
      Vl[kv][d + 0] = bfu(v.x); Vl[kv][d + 1] = bfu(v.y);
      Vl[kv][d + 2] = bfu(v.z); Vl[kv][d + 3] = bfu(v.w);
    }
    __syncthreads();
    #pragma unroll
    for (int i = 0; i < 8; ++i) {
      const int idx = i * 1024 + threadIdx.x * 4;
      const int d = idx >> 6, kv = idx & 63;
      ushort4 o = make_ushort4(Vl[kv + 0][d], Vl[kv + 1][d], Vl[kv + 2][d], Vl[kv + 3][d]);
      *(ushort4*)(vt + ((size_t)colx * 32 + t) * 8192 + d * 64 + kv) = o;
    }
  }
}

// ============ fallback attention (fp32 staging) ============
__global__ __launch_bounds__(512, 2) void attn_fallback(
    const float* __restrict__ qg, const float* __restrict__ kg,
    const float* __restrict__ vg, const float* __restrict__ sinkg,
    float* __restrict__ outg)
{
  const int col = (blockIdx.x & 7) + 8 * ((blockIdx.x >> 3) & 1);
  const int rank = blockIdx.x >> 4;
  const int qtile = rank < 24 ? rank + 8 : 31 - rank;
  const int hkv = col & 7, b = col >> 3;
  const int qb = qtile * 64;
  const int tid = threadIdx.x;
  const int wave = tid >> 6, lane = tid & 63;
  const int c5 = lane & 31, hi = lane >> 5;
  const int hq = (hkv << 2) + (wave >> 1);
  const int qw = qb + (wave & 1) * 32;
  const int qrow = qw + c5;

  __shared__ __align__(16) __bf16 Kl[2][64 * 128];
  __shared__ __align__(16) __bf16 Vt[2][128 * 64];

  const float LOG2E = 1.4426950408889634f;
  const float scale = 0.08838834764831845f * LOG2E;
  const float THR = 12.0f;

  bf16x8 qf[8];
  {
    const float* qp = qg + (((size_t)b * SS + qrow) * HQ + hq) * DD + hi * 8;
    #pragma unroll
    for (int ch = 0; ch < 8; ++ch) {
      float4 a = *(const float4*)(qp + ch * 16);
      float4 a2 = *(const float4*)(qp + ch * 16 + 4);
      qf[ch] = cvt8(a, a2, scale);
    }
  }
  const float sk = sinkg[hq] * LOG2E;

  float mm = -1e30f, ll = 0.f;
  f32x16 acc[4];
  #pragma unroll
  for (int d = 0; d < 4; ++d)
    #pragma unroll
    for (int r = 0; r < 16; ++r) acc[d][r] = 0.f;

  const int t0 = (qb > (WIN - 1) ? (qb - (WIN - 1)) : 0) >> 6;
  const int t1 = (qb + 63) >> 6;

  const int krow = tid >> 3, kchunk = tid & 7;
  const int vd = tid & 127, vslot = tid >> 7;
  const size_t KSTEP = (size_t)64 * HKV * DD;
  const float* kBase = kg + (((size_t)b * SS + krow) * HKV + hkv) * DD + kchunk * 16;
  const float* vBase = vg + (((size_t)b * SS + vslot * 16) * HKV + hkv) * DD + vd;

  float4 k0, k1, k2, k3; float vr[16];
  auto issue = [&](int t) {
    const float* kp = kBase + (size_t)t * KSTEP;
    k0 = *(const float4*)(kp);     k1 = *(const float4*)(kp + 4);
    k2 = *(const float4*)(kp + 8); k3 = *(const float4*)(kp + 12);
    const float* vp = vBase + (size_t)t * KSTEP;
    #pragma unroll
    for (int j = 0; j < 16; ++j) vr[j] = vp[(size_t)j * (HKV * DD)];
  };
  const int ksw = SWZ(krow);
  const int vsw = SWZ(vd);
  auto commit = [&](int buf) {
    char* kd = (char*)(&Kl[buf][0]) + krow * 256;
    *(bf16x8*)(kd + ((kchunk * 32) ^ ksw)) = cvt8(k0, k1, 1.f);
    *(bf16x8*)(kd + ((kchunk * 32 + 16) ^ ksw)) = cvt8(k2, k3, 1.f);
    char* vdst = (char*)(&Vt[buf][0]) + vd * 128;
    bf16x8 w0, w1;
    #pragma unroll
    for (int j = 0; j < 8; ++j) { w0[j] = (__bf16)vr[j]; w1[j] = (__bf16)vr[8 + j]; }
    *(bf16x8*)(vdst + ((vslot * 32) ^ vsw)) = w0;
    *(bf16x8*)(vdst + ((vslot * 32 + 16) ^ vsw)) = w1;
  };

  issue(t0);
  commit(0);
  __syncthreads();
  int cur = 0;

  const int swA = SWZ(c5);
  const int swB = swA ^ 0x40;

  for (int t = t0; t <= t1; ++t) {
    if (t < t1) issue(t + 1);
    const int kb = t << 6;
    if (kb <= qw + 31 && kb + 63 >= qw - (WIN - 1)) {
      const char* Ksc = (const char*)&Kl[cur][0];
      const char* Vsc = (const char*)&Vt[cur][0];
      f32x16 s0, s1;
      #pragma unroll
      for (int r = 0; r < 16; ++r) { s0[r] = 0.f; s1[r] = 0.f; }
      #pragma unroll
      for (int ch = 0; ch < 8; ++ch) {
        const int colb = ch * 32 + hi * 16;
        bf16x8 a0 = *(const bf16x8*)(Ksc + c5 * 256 + (colb ^ swA));
        bf16x8 a1 = *(const bf16x8*)(Ksc + (32 + c5) * 256 + (colb ^ swB));
        s0 = __builtin_amdgcn_mfma_f32_32x32x16_bf16(a0, qf[ch], s0, 0, 0, 0);
        s1 = __builtin_amdgcn_mfma_f32_32x32x16_bf16(a1, qf[ch], s1, 0, 0, 0);
      }
      const bool noMask = (kb + 63 <= qw) && (kb >= qw - (WIN - 32));
      if (!noMask) {
        #pragma unroll
        for (int r = 0; r < 16; ++r) {
          const int lr = (r & 3) + 8 * (r >> 2) + 4 * hi;
          const int kv0 = kb + lr, kv1 = kv0 + 32;
          const bool ok0 = (kv0 <= qrow) && (qrow - kv0 < WIN);
          const bool ok1 = (kv1 <= qrow) && (qrow - kv1 < WIN);
          s0[r] = ok0 ? s0[r] : -1e30f;
          s1[r] = ok1 ? s1[r] : -1e30f;
        }
      }
      float tmax = s0[0];
      #pragma unroll
      for (int r = 1; r < 16; ++r) tmax = fmaxf(tmax, s0[r]);
      #pragma unroll
      for (int r = 0; r < 16; ++r) tmax = fmaxf(tmax, s1[r]);
      tmax = fmaxf(tmax, __shfl_xor(tmax, 32));
      const bool resc = __any(tmax > mm + THR);
      const float mnew = resc ? fmaxf(mm, tmax) : mm;
      float tsum = 0.f;
      #pragma unroll
      for (int r = 0; r < 16; ++r) {
        s0[r] = (s0[r] > -9e29f) ? exp2f(s0[r] - mnew) : 0.f; tsum += s0[r];
        s1[r] = (s1[r] > -9e29f) ? exp2f(s1[r] - mnew) : 0.f; tsum += s1[r];
      }
      tsum += __shfl_xor(tsum, 32);
      if (resc) {
        const float scl = exp2f(mm - mnew);
        ll = ll * scl + tsum;
        #pragma unroll
        for (int d = 0; d < 4; ++d)
          #pragma unroll
          for (int r = 0; r < 16; ++r) acc[d][r] *= scl;
        mm = mnew;
      } else {
        ll += tsum;
      }
      bf16x8 pb[4];
      #pragma unroll
      for (int kvq = 0; kvq < 4; ++kvq) {
        const int bq = (kvq & 1) * 8;
        float e0, e1, e2, e3, e4, e5, e6, e7;
        if (kvq & 2) {
          e0 = s1[bq+0]; e1 = s1[bq+1]; e2 = s1[bq+2]; e3 = s1[bq+3];
          e4 = s1[bq+4]; e5 = s1[bq+5]; e6 = s1[bq+6]; e7 = s1[bq+7];
        } else {
          e0 = s0[bq+0]; e1 = s0[bq+1]; e2 = s0[bq+2]; e3 = s0[bq+3];
          e4 = s0[bq+4]; e5 = s0[bq+5]; e6 = s0[bq+6]; e7 = s0[bq+7];
        }
        const uint32_t A0 = pk2(e0, e1), A1 = pk2(e2, e3);
        const uint32_t B0 = pk2(e4, e5), B1 = pk2(e6, e7);
        const uint32_t XA0 = __shfl_xor(A0, 32), XA1 = __shfl_xor(A1, 32);
        const uint32_t XB0 = __shfl_xor(B0, 32), XB1 = __shfl_xor(B1, 32);
        union { uint4 u; bf16x8 v; } cvu;
        cvu.u.x = hi ? XB0 : A0;
        cvu.u.y = hi ? XB1 : A1;
        cvu.u.z = hi ? B0 : XA0;
        cvu.u.w = hi ? B1 : XA1;
        pb[kvq] = cvu.v;
      }
      #pragma unroll
      for (int d = 0; d < 4; ++d) {
        const int rowb = (d * 32 + c5) * 128;
        const int swV = swA ^ ((d & 1) << 6);
        #pragma unroll
        for (int kvq = 0; kvq < 4; ++kvq) {
          bf16x8 va = *(const bf16x8*)(Vsc + rowb + ((kvq * 32 + hi * 16) ^ swV));
          acc[d] = __builtin_amdgcn_mfma_f32_32x32x16_bf16(va, pb[kvq], acc[d], 0, 0, 0);
        }
      }
    }
    if (t < t1) {
      commit(cur ^ 1);
      __syncthreads();
      cur ^= 1;
    }
  }
  {
    const float Mf = fmaxf(mm, sk);
    const float ex = exp2f(mm - Mf);
    const float denom = ll * ex + exp2f(sk - Mf);
    const float fac = ex / denom;
    float* orow = outg + (((size_t)b * SS + qrow) * HQ + hq) * DD;
    #pragma unroll
    for (int d = 0; d < 4; ++d) {
      #pragma unroll
      for (int q4 = 0; q4 < 4; ++q4) {
        float4 o;
        o.x = acc[d][q4 * 4 + 0] * fac;
        o.y = acc[d][q4 * 4 + 1] * fac;
        o.z = acc[d][q4 * 4 + 2] * fac;
        o.w = acc[d][q4 * 4 + 3] * fac;
        *(float4*)(orow + d * 32 + q4 * 8 + 4 * hi) = o;
      }
    }
  }
}

// ---- cache path ----
__global__ void build_inv(const int* __restrict__ ids, int* __restrict__ inv,
                          int npages, int nslots) {
  const int i = threadIdx.x;
  if (i < npages) inv[i] = -1;
  __syncthreads();
  if (i < nslots) inv[ids[i]] = i;
}

__global__ void page_fill(const float* __restrict__ kg, const float* __restrict__ vg,
                          const float* __restrict__ cache_in, const int* __restrict__ inv,
                          float* __restrict__ cache) {
  const int page = blockIdx.x, half = blockIdx.y;
  const int slot = inv[page];
  float4* d4 = (float4*)cache;
  const size_t dbase = (((size_t)page * 2 + half) * 8) * 1024;
  if (slot >= 0) {
    const int b = slot >> 6, blk = slot & 63;
    const float4* s4 = (const float4*)(half ? vg : kg);
    for (int f = threadIdx.x; f < 8192; f += blockDim.x) {
      const int d = f & 31, s = (f >> 5) & 31, h = f >> 10;
      d4[dbase + (size_t)h * 1024 + s * 32 + d] =
          s4[(((size_t)b * SS + blk * 32 + s) * 8 + h) * 32 + d];
    }
  } else {
    const float4* s4 = (const float4*)cache_in;
    for (int f = threadIdx.x; f < 8192; f += blockDim.x)
      d4[dbase + f] = s4[dbase + f];
  }
}

__global__ void cache_copy(const float* __restrict__ src, float* __restrict__ dst, int n4) {
  const float4* s = (const float4*)src;
  float4* d = (float4*)dst;
  for (int i = blockIdx.x * blockDim.x + threadIdx.x; i < n4; i += gridDim.x * blockDim.x)
    d[i] = s[i];
}
__global__ void cache_scatter(const float* __restrict__ kg, const float* __restrict__ vg,
                              const int* __restrict__ ids, float* __restrict__ cache) {
  const int slot = blockIdx.x;
  const int half = blockIdx.y;
  const int b = slot >> 6, blk = slot & 63;
  const int page = ids[slot];
  const float4* s4 = (const float4*)(half ? vg : kg);
  float4* d4 = (float4*)cache;
  for (int f = threadIdx.x; f < 8192; f += blockDim.x) {
    const int d = f & 31, s = (f >> 5) & 31, h = f >> 10;
    d4[(((size_t)page * 2 + half) * 8 + h) * 1024 + s * 32 + d] =
        s4[(((size_t)b * SS + blk * 32 + s) * 8 + h) * 32 + d];
  }
}

extern "C" void kernel_launch(void* const* d_in, const int* in_sizes, int n_in,
                              void* d_out, int out_size, void* d_ws, size_t ws_size,
                              hipStream_t stream) {
  const float* q = (const float*)d_in[0];
  const float* k = (const float*)d_in[1];
  const float* v = (const float*)d_in[2];
  const float* cache_in = (const float*)d_in[3];
  const int* ids = (const int*)d_in[4];
  const float* sink = (const float*)d_in[5];
  float* out = (float*)d_out;
  float* cache_out = out + (size_t)BB * SS * HQ * DD;

  const int nslots = in_sizes[4];                       // 128
  const int npages = in_sizes[3] / (2 * HKV * 32 * DD); // 128

  const size_t kvBytes = (size_t)BB * HKV * SS * DD * 2; // 8,388,608 each
  const size_t needFull = 4096 + 2 * kvBytes;
  const size_t dumpBytes = (size_t)512 * 512 * 4 * sizeof(float); // 4 MB
  const size_t needAbl = needFull + dumpBytes;
  const bool smallMaps = (npages <= 1024) && (nslots <= 1024);

  if (ws_size >= needFull && smallMaps) {
    int* inv = (int*)d_ws;
    unsigned short* kbp = (unsigned short*)((char*)d_ws + 4096);
    unsigned short* vtp = kbp + kvBytes / 2;
    build_inv<<<1, 1024, 0, stream>>>(ids, inv, npages, nslots);
    page_fill<<<dim3(npages, 2), 256, 0, stream>>>(k, v, cache_in, inv, cache_out);
    prep_kv<<<dim3(BB * HKV * 32, 2), 256, 0, stream>>>(k, v, kbp, vtp);
    if (ws_size >= needAbl) {
      float* dump = (float*)((char*)d_ws + needFull);
      ab_loads<<<512, 512, 0, stream>>>(q, kbp, vtp, dump);
      ab_qk<<<512, 512, 0, stream>>>(q, kbp, vtp, dump);
      ab_sm<<<512, 512, 0, stream>>>(q, kbp, vtp, dump);
    }
    attn_kernel<<<512, 512, 0, stream>>>(q, sink, out, kbp, vtp);
  } else if (ws_size >= (size_t)npages * sizeof(int) && smallMaps) {
    int* inv = (int*)d_ws;
    build_inv<<<1, 1024, 0, stream>>>(ids, inv, npages, nslots);
    page_fill<<<dim3(npages, 2), 256, 0, stream>>>(k, v, cache_in, inv, cache_out);
    attn_fallback<<<512, 512, 0, stream>>>(q, k, v, sink, out);
  } else {
    cache_copy<<<4096, 256, 0, stream>>>(cache_in, cache_out, (BB * SS * HKV * DD * 2) / 4);
    cache_scatter<<<dim3(BB * 64, 2), 256, 0, stream>>>(k, v, ids, cache_out);
    attn_fallback<<<512, 512, 0, stream>>>(q, k, v, sink, out);
  }
}

// Round 16
// 107.351 us; speedup vs baseline: 2.3752x; 2.3752x over previous
//
#include <hip/hip_runtime.h>
#include <hip/hip_bf16.h>
#include <stdint.h>

#define BB 2
#define SS 2048
#define HQ 32
#define HKV 8
#define DD 128
#define WIN 512

typedef __bf16 bf16x8 __attribute__((ext_vector_type(8)));
typedef float f32x16 __attribute__((ext_vector_type(16)));
typedef unsigned int u32;
typedef __attribute__((address_space(3))) u32 lds_u32;
typedef const __attribute__((address_space(1))) u32 glb_u32;

__device__ __forceinline__ void gld_lds16(const void* g, void* l) {
  __builtin_amdgcn_global_load_lds((glb_u32*)g, (lds_u32*)l, 16, 0, 0);
}

__device__ __forceinline__ bf16x8 cvt8(float4 a, float4 b, float s) {
  bf16x8 r;
  r[0] = (__bf16)(a.x * s); r[1] = (__bf16)(a.y * s);
  r[2] = (__bf16)(a.z * s); r[3] = (__bf16)(a.w * s);
  r[4] = (__bf16)(b.x * s); r[5] = (__bf16)(b.y * s);
  r[6] = (__bf16)(b.z * s); r[7] = (__bf16)(b.w * s);
  return r;
}

__device__ __forceinline__ uint32_t pk2(float lo, float hi) {
  uint32_t w;
  asm("v_cvt_pk_bf16_f32 %0, %1, %2" : "=v"(w) : "v"(lo), "v"(hi));
  return w;
}

__device__ __forceinline__ unsigned short bfu(float x) {
  union { __bf16 b; unsigned short u; } c; c.b = (__bf16)x; return c.u;
}

#define SWZ(r) ((((r) ^ ((r) >> 3)) & 7) << 4)

// ============ main attention ============
// grid 512 blocks (XCD-pinned, longest-first), block 512 = 8 waves.
// Block: 128 q-rows x 2 heads.  wave = (wq = wave&3 : 32-row slot, wh = wave>>2 : head).
// KVBLK=64, 32x32x16 MFMA, P in registers. Staging via global_load_lds from
// pre-swizzled tile images (LDS dest linear; swizzle baked into image by prep_kv).
__global__ __launch_bounds__(512, 2) void attn_kernel(
    const float* __restrict__ qg, const float* __restrict__ sinkg,
    float* __restrict__ outg, const char* __restrict__ kvimg)
{
  const int sid = (blockIdx.x & 7) * 64 + (blockIdx.x >> 3);
  const int col = sid >> 5;            // (b,hkv): 2 cols per XCD
  const int r = sid & 31;
  const int hp = r & 1;                // head pair
  const int qtile = 15 - (r >> 1);     // longest-first (128-row tiles)
  const int hkv = col & 7, b = col >> 3;
  const int qb = qtile * 128;
  const int tid = threadIdx.x;
  const int wave = tid >> 6, lane = tid & 63;
  const int c5 = lane & 31, hi = lane >> 5;
  const int wq = wave & 3, wh = wave >> 2;
  const int hq = (hkv << 2) + hp * 2 + wh;
  const int qw = qb + wq * 32;
  const int qrow = qw + c5;

  __shared__ __align__(16) char Buf[2][32768];  // [K image 16KB | V image 16KB]

  const float LOG2E = 1.4426950408889634f;
  const float scale = 0.08838834764831845f * LOG2E;
  const float THR = 12.0f;

  // Q fragments: B-operand of S^T = K Q^T.  col=q=c5, k(d) = ch*16 + 8*hi + j
  bf16x8 qf[8];
  {
    const float* qp = qg + (((size_t)b * SS + qrow) * HQ + hq) * DD + hi * 8;
    #pragma unroll
    for (int ch = 0; ch < 8; ++ch) {
      float4 a = *(const float4*)(qp + ch * 16);
      float4 a2 = *(const float4*)(qp + ch * 16 + 4);
      qf[ch] = cvt8(a, a2, scale);
    }
  }
  const float sk = sinkg[hq] * LOG2E;

  float mm = -1e30f, ll = 0.f;
  f32x16 acc[4];
  #pragma unroll
  for (int d = 0; d < 4; ++d)
    #pragma unroll
    for (int r2 = 0; r2 < 16; ++r2) acc[d][r2] = 0.f;

  const int t0 = (qb > 511 ? (qb - 511) >> 6 : 0);
  const int t1 = (qb + 127) >> 6;

  const char* colbase = kvimg + (size_t)col * (32 * 32768);
  auto stage = [&](int t, int buf) {
    const char* src = colbase + (size_t)t * 32768 + wave * 4096 + lane * 16;
    char* dst = &Buf[buf][wave * 4096];
    #pragma unroll
    for (int i = 0; i < 4; ++i)
      gld_lds16(src + i * 1024, dst + i * 1024);
  };

  stage(t0, 0);
  __syncthreads();
  int cur = 0;

  const int swA = SWZ(c5);
  const int swB = swA ^ 0x40;

  for (int t = t0; t <= t1; ++t) {
    if (t < t1) stage(t + 1, cur ^ 1);   // DMA into other buffer; drained at barrier
    const int kb = t << 6;

    if (kb <= qw + 31 && kb + 63 >= qw - (WIN - 1)) {
      const char* Ksc = &Buf[cur][0];
      const char* Vsc = &Buf[cur][16384];

      // ---- QK^T: S^T[64 kv][32 q] ----
      f32x16 s0, s1;
      #pragma unroll
      for (int r2 = 0; r2 < 16; ++r2) { s0[r2] = 0.f; s1[r2] = 0.f; }
      __builtin_amdgcn_s_setprio(1);
      #pragma unroll
      for (int ch = 0; ch < 8; ++ch) {
        const int colb = ch * 32 + hi * 16;
        bf16x8 a0 = *(const bf16x8*)(Ksc + c5 * 256 + (colb ^ swA));
        bf16x8 a1 = *(const bf16x8*)(Ksc + (32 + c5) * 256 + (colb ^ swB));
        s0 = __builtin_amdgcn_mfma_f32_32x32x16_bf16(a0, qf[ch], s0, 0, 0, 0);
        s1 = __builtin_amdgcn_mfma_f32_32x32x16_bf16(a1, qf[ch], s1, 0, 0, 0);
      }
      __builtin_amdgcn_s_setprio(0);

      const bool noMask = (kb + 63 <= qw) && (kb >= qw - (WIN - 32));

      if (!noMask) {
        #pragma unroll
        for (int r2 = 0; r2 < 16; ++r2) {
          const int lr = (r2 & 3) + 8 * (r2 >> 2) + 4 * hi;
          const int kv0 = kb + lr, kv1 = kv0 + 32;
          const bool ok0 = (kv0 <= qrow) && (qrow - kv0 < WIN);
          const bool ok1 = (kv1 <= qrow) && (qrow - kv1 < WIN);
          s0[r2] = ok0 ? s0[r2] : -1e30f;
          s1[r2] = ok1 ? s1[r2] : -1e30f;
        }
      }
      float tmax = s0[0];
      #pragma unroll
      for (int r2 = 1; r2 < 16; ++r2) tmax = fmaxf(tmax, s0[r2]);
      #pragma unroll
      for (int r2 = 0; r2 < 16; ++r2) tmax = fmaxf(tmax, s1[r2]);
      tmax = fmaxf(tmax, __shfl_xor(tmax, 32));

      const bool resc = __any(tmax > mm + THR);
      const float mnew = resc ? fmaxf(mm, tmax) : mm;
      float tsum = 0.f;
      if (noMask) {
        #pragma unroll
        for (int r2 = 0; r2 < 16; ++r2) {
          s0[r2] = exp2f(s0[r2] - mnew); tsum += s0[r2];
          s1[r2] = exp2f(s1[r2] - mnew); tsum += s1[r2];
        }
      } else {
        #pragma unroll
        for (int r2 = 0; r2 < 16; ++r2) {
          s0[r2] = (s0[r2] > -9e29f) ? exp2f(s0[r2] - mnew) : 0.f; tsum += s0[r2];
          s1[r2] = (s1[r2] > -9e29f) ? exp2f(s1[r2] - mnew) : 0.f; tsum += s1[r2];
        }
      }
      tsum += __shfl_xor(tsum, 32);

      if (resc) {
        const float scl = exp2f(mm - mnew);
        ll = ll * scl + tsum;
        #pragma unroll
        for (int d = 0; d < 4; ++d)
          #pragma unroll
          for (int r2 = 0; r2 < 16; ++r2) acc[d][r2] *= scl;
        mm = mnew;
      } else {
        ll += tsum;
      }

      // ---- P^T B-frags in-register: lane<->lane^32 exchange ----
      bf16x8 pb[4];
      #pragma unroll
      for (int kvq = 0; kvq < 4; ++kvq) {
        const int bq = (kvq & 1) * 8;
        float e0, e1, e2, e3, e4, e5, e6, e7;
        if (kvq & 2) {
          e0 = s1[bq+0]; e1 = s1[bq+1]; e2 = s1[bq+2]; e3 = s1[bq+3];
          e4 = s1[bq+4]; e5 = s1[bq+5]; e6 = s1[bq+6]; e7 = s1[bq+7];
        } else {
          e0 = s0[bq+0]; e1 = s0[bq+1]; e2 = s0[bq+2]; e3 = s0[bq+3];
          e4 = s0[bq+4]; e5 = s0[bq+5]; e6 = s0[bq+6]; e7 = s0[bq+7];
        }
        const uint32_t A0 = pk2(e0, e1), A1 = pk2(e2, e3);
        const uint32_t B0 = pk2(e4, e5), B1 = pk2(e6, e7);
        const uint32_t XA0 = __shfl_xor(A0, 32), XA1 = __shfl_xor(A1, 32);
        const uint32_t XB0 = __shfl_xor(B0, 32), XB1 = __shfl_xor(B1, 32);
        union { uint4 u; bf16x8 v; } cvu;
        cvu.u.x = hi ? XB0 : A0;
        cvu.u.y = hi ? XB1 : A1;
        cvu.u.z = hi ? B0 : XA0;
        cvu.u.w = hi ? B1 : XA1;
        pb[kvq] = cvu.v;
      }

      // ---- PV: O^T[d][q] = V^T P^T ----
      __builtin_amdgcn_s_setprio(1);
      #pragma unroll
      for (int d = 0; d < 4; ++d) {
        const int rowb = (d * 32 + c5) * 128;
        const int swV = swA ^ ((d & 1) << 6);
        #pragma unroll
        for (int kvq = 0; kvq < 4; ++kvq) {
          bf16x8 va = *(const bf16x8*)(Vsc + rowb + ((kvq * 32 + hi * 16) ^ swV));
          acc[d] = __builtin_amdgcn_mfma_f32_32x32x16_bf16(va, pb[kvq], acc[d], 0, 0, 0);
        }
      }
      __builtin_amdgcn_s_setprio(0);
    }

    if (t < t1) {
      __syncthreads();   // drains DMA (vmcnt) + separates buffer roles
      cur ^= 1;
    }
  }

  // ---- epilogue: sink + normalize (lane-local), float4 stores ----
  {
    const float Mf = fmaxf(mm, sk);
    const float ex = exp2f(mm - Mf);
    const float denom = ll * ex + exp2f(sk - Mf);
    const float fac = ex / denom;
    float* orow = outg + (((size_t)b * SS + qrow) * HQ + hq) * DD;
    #pragma unroll
    for (int d = 0; d < 4; ++d) {
      #pragma unroll
      for (int q4 = 0; q4 < 4; ++q4) {
        float4 o;
        o.x = acc[d][q4 * 4 + 0] * fac;
        o.y = acc[d][q4 * 4 + 1] * fac;
        o.z = acc[d][q4 * 4 + 2] * fac;
        o.w = acc[d][q4 * 4 + 3] * fac;
        *(float4*)(orow + d * 32 + q4 * 8 + 4 * hi) = o;
      }
    }
  }
}

// ============ prep: fp32 K/V -> combined pre-swizzled bf16 LDS images ============
// kvimg[col][tile] = [Kimg 16KB | Vimg 16KB], exactly the LDS byte image:
//   Kimg[kr*128 + j] = bf16(K[b, kb+kr, hkv, j ^ kxor(kr)])   (elem idx, kxor=SWZ>>1)
//   Vimg[vd*64  + j] = bf16(V[b, kb + (j ^ vxor(vd)), hkv, vd])
// grid (16*32, 2), 256 threads
__global__ void prep_kv(const float* __restrict__ kg, const float* __restrict__ vg,
                        char* __restrict__ kvimg) {
  const int t = blockIdx.x & 31, colx = blockIdx.x >> 5;
  const int b = colx >> 3, hkv = colx & 7;
  const int kb = t * 64;
  unsigned short* img = (unsigned short*)(kvimg + (size_t)colx * (32 * 32768) + (size_t)t * 32768);
  if (blockIdx.y == 0) {
    #pragma unroll
    for (int i = 0; i < 8; ++i) {
      const int c = i * 256 + threadIdx.x;       // [0,2048) 4-elem chunks
      const int kr = c >> 5, j0 = (c & 31) * 4;
      const int kx = ((kr ^ (kr >> 3)) & 7) << 3;
      const float* sp = kg + (((size_t)b * SS + kb + kr) * HKV + hkv) * DD + (j0 ^ kx);
      float4 a = *(const float4*)sp;
      *(ushort4*)(img + kr * 128 + j0) = make_ushort4(bfu(a.x), bfu(a.y), bfu(a.z), bfu(a.w));
    }
  } else {
    unsigned short* vimg = img + 8192;
    __shared__ unsigned short Vl[64][132];
    #pragma unroll
    for (int i = 0; i < 8; ++i) {
      const int idx = i * 1024 + threadIdx.x * 4;
      const int kv = idx >> 7, d = idx & 127;
      float4 v = *(const float4*)(vg + (((size_t)b * SS + kb + kv) * HKV + hkv) * DD + d);
      Vl[kv][d + 0] = bfu(v.x); Vl[kv][d + 1] = bfu(v.y);
      Vl[kv][d + 2] = bfu(v.z); Vl[kv][d + 3] = bfu(v.w);
    }
    __syncthreads();
    #pragma unroll
    for (int i = 0; i < 8; ++i) {
      const int c = i * 256 + threadIdx.x;       // [0,2048)
      const int vd = c >> 4, j0 = (c & 15) * 4;
      const int vx = ((vd ^ (vd >> 3)) & 7) << 3;
      const int js = j0 ^ vx;
      *(ushort4*)(vimg + vd * 64 + j0) =
          make_ushort4(Vl[js + 0][vd], Vl[js + 1][vd], Vl[js + 2][vd], Vl[js + 3][vd]);
    }
  }
}

// ============ fallback attention (fp32 LDS staging, no workspace needed) ============
__global__ __launch_bounds__(512, 2) void attn_fallback(
    const float* __restrict__ qg, const float* __restrict__ kg,
    const float* __restrict__ vg, const float* __restrict__ sinkg,
    float* __restrict__ outg)
{
  const int col = (blockIdx.x & 7) + 8 * ((blockIdx.x >> 3) & 1);
  const int rank = blockIdx.x >> 4;
  const int qtile = rank < 24 ? rank + 8 : 31 - rank;
  const int hkv = col & 7, b = col >> 3;
  const int qb = qtile * 64;
  const int tid = threadIdx.x;
  const int wave = tid >> 6, lane = tid & 63;
  const int c5 = lane & 31, hi = lane >> 5;
  const int hq = (hkv << 2) + (wave >> 1);
  const int qw = qb + (wave & 1) * 32;
  const int qrow = qw + c5;

  __shared__ __align__(16) __bf16 Kl[2][64 * 128];
  __shared__ __align__(16) __bf16 Vt[2][128 * 64];

  const float LOG2E = 1.4426950408889634f;
  const float scale = 0.08838834764831845f * LOG2E;
  const float THR = 12.0f;

  bf16x8 qf[8];
  {
    const float* qp = qg + (((size_t)b * SS + qrow) * HQ + hq) * DD + hi * 8;
    #pragma unroll
    for (int ch = 0; ch < 8; ++ch) {
      float4 a = *(const float4*)(qp + ch * 16);
      float4 a2 = *(const float4*)(qp + ch * 16 + 4);
      qf[ch] = cvt8(a, a2, scale);
    }
  }
  const float sk = sinkg[hq] * LOG2E;

  float mm = -1e30f, ll = 0.f;
  f32x16 acc[4];
  #pragma unroll
  for (int d = 0; d < 4; ++d)
    #pragma unroll
    for (int r = 0; r < 16; ++r) acc[d][r] = 0.f;

  const int t0 = (qb > (WIN - 1) ? (qb - (WIN - 1)) : 0) >> 6;
  const int t1 = (qb + 63) >> 6;

  const int krow = tid >> 3, kchunk = tid & 7;
  const int vd = tid & 127, vslot = tid >> 7;
  const size_t KSTEP = (size_t)64 * HKV * DD;
  const float* kBase = kg + (((size_t)b * SS + krow) * HKV + hkv) * DD + kchunk * 16;
  const float* vBase = vg + (((size_t)b * SS + vslot * 16) * HKV + hkv) * DD + vd;

  float4 k0, k1, k2, k3; float vr[16];
  auto issue = [&](int t) {
    const float* kp = kBase + (size_t)t * KSTEP;
    k0 = *(const float4*)(kp);     k1 = *(const float4*)(kp + 4);
    k2 = *(const float4*)(kp + 8); k3 = *(const float4*)(kp + 12);
    const float* vp = vBase + (size_t)t * KSTEP;
    #pragma unroll
    for (int j = 0; j < 16; ++j) vr[j] = vp[(size_t)j * (HKV * DD)];
  };
  const int ksw = SWZ(krow);
  const int vsw = SWZ(vd);
  auto commit = [&](int buf) {
    char* kd = (char*)(&Kl[buf][0]) + krow * 256;
    *(bf16x8*)(kd + ((kchunk * 32) ^ ksw)) = cvt8(k0, k1, 1.f);
    *(bf16x8*)(kd + ((kchunk * 32 + 16) ^ ksw)) = cvt8(k2, k3, 1.f);
    char* vdst = (char*)(&Vt[buf][0]) + vd * 128;
    bf16x8 w0, w1;
    #pragma unroll
    for (int j = 0; j < 8; ++j) { w0[j] = (__bf16)vr[j]; w1[j] = (__bf16)vr[8 + j]; }
    *(bf16x8*)(vdst + ((vslot * 32) ^ vsw)) = w0;
    *(bf16x8*)(vdst + ((vslot * 32 + 16) ^ vsw)) = w1;
  };

  issue(t0);
  commit(0);
  __syncthreads();
  int cur = 0;

  const int swA = SWZ(c5);
  const int swB = swA ^ 0x40;

  for (int t = t0; t <= t1; ++t) {
    if (t < t1) issue(t + 1);
    const int kb = t << 6;
    if (kb <= qw + 31 && kb + 63 >= qw - (WIN - 1)) {
      const char* Ksc = (const char*)&Kl[cur][0];
      const char* Vsc = (const char*)&Vt[cur][0];
      f32x16 s0, s1;
      #pragma unroll
      for (int r = 0; r < 16; ++r) { s0[r] = 0.f; s1[r] = 0.f; }
      #pragma unroll
      for (int ch = 0; ch < 8; ++ch) {
        const int colb = ch * 32 + hi * 16;
        bf16x8 a0 = *(const bf16x8*)(Ksc + c5 * 256 + (colb ^ swA));
        bf16x8 a1 = *(const bf16x8*)(Ksc + (32 + c5) * 256 + (colb ^ swB));
        s0 = __builtin_amdgcn_mfma_f32_32x32x16_bf16(a0, qf[ch], s0, 0, 0, 0);
        s1 = __builtin_amdgcn_mfma_f32_32x32x16_bf16(a1, qf[ch], s1, 0, 0, 0);
      }
      const bool noMask = (kb + 63 <= qw) && (kb >= qw - (WIN - 32));
      if (!noMask) {
        #pragma unroll
        for (int r = 0; r < 16; ++r) {
          const int lr = (r & 3) + 8 * (r >> 2) + 4 * hi;
          const int kv0 = kb + lr, kv1 = kv0 + 32;
          const bool ok0 = (kv0 <= qrow) && (qrow - kv0 < WIN);
          const bool ok1 = (kv1 <= qrow) && (qrow - kv1 < WIN);
          s0[r] = ok0 ? s0[r] : -1e30f;
          s1[r] = ok1 ? s1[r] : -1e30f;
        }
      }
      float tmax = s0[0];
      #pragma unroll
      for (int r = 1; r < 16; ++r) tmax = fmaxf(tmax, s0[r]);
      #pragma unroll
      for (int r = 0; r < 16; ++r) tmax = fmaxf(tmax, s1[r]);
      tmax = fmaxf(tmax, __shfl_xor(tmax, 32));
      const bool resc = __any(tmax > mm + THR);
      const float mnew = resc ? fmaxf(mm, tmax) : mm;
      float tsum = 0.f;
      #pragma unroll
      for (int r = 0; r < 16; ++r) {
        s0[r] = (s0[r] > -9e29f) ? exp2f(s0[r] - mnew) : 0.f; tsum += s0[r];
        s1[r] = (s1[r] > -9e29f) ? exp2f(s1[r] - mnew) : 0.f; tsum += s1[r];
      }
      tsum += __shfl_xor(tsum, 32);
      if (resc) {
        const float scl = exp2f(mm - mnew);
        ll = ll * scl + tsum;
        #pragma unroll
        for (int d = 0; d < 4; ++d)
          #pragma unroll
          for (int r = 0; r < 16; ++r) acc[d][r] *= scl;
        mm = mnew;
      } else {
        ll += tsum;
      }
      bf16x8 pb[4];
      #pragma unroll
      for (int kvq = 0; kvq < 4; ++kvq) {
        const int bq = (kvq & 1) * 8;
        float e0, e1, e2, e3, e4, e5, e6, e7;
        if (kvq & 2) {
          e0 = s1[bq+0]; e1 = s1[bq+1]; e2 = s1[bq+2]; e3 = s1[bq+3];
          e4 = s1[bq+4]; e5 = s1[bq+5]; e6 = s1[bq+6]; e7 = s1[bq+7];
        } else {
          e0 = s0[bq+0]; e1 = s0[bq+1]; e2 = s0[bq+2]; e3 = s0[bq+3];
          e4 = s0[bq+4]; e5 = s0[bq+5]; e6 = s0[bq+6]; e7 = s0[bq+7];
        }
        const uint32_t A0 = pk2(e0, e1), A1 = pk2(e2, e3);
        const uint32_t B0 = pk2(e4, e5), B1 = pk2(e6, e7);
        const uint32_t XA0 = __shfl_xor(A0, 32), XA1 = __shfl_xor(A1, 32);
        const uint32_t XB0 = __shfl_xor(B0, 32), XB1 = __shfl_xor(B1, 32);
        union { uint4 u; bf16x8 v; } cvu;
        cvu.u.x = hi ? XB0 : A0;
        cvu.u.y = hi ? XB1 : A1;
        cvu.u.z = hi ? B0 : XA0;
        cvu.u.w = hi ? B1 : XA1;
        pb[kvq] = cvu.v;
      }
      #pragma unroll
      for (int d = 0; d < 4; ++d) {
        const int rowb = (d * 32 + c5) * 128;
        const int swV = swA ^ ((d & 1) << 6);
        #pragma unroll
        for (int kvq = 0; kvq < 4; ++kvq) {
          bf16x8 va = *(const bf16x8*)(Vsc + rowb + ((kvq * 32 + hi * 16) ^ swV));
          acc[d] = __builtin_amdgcn_mfma_f32_32x32x16_bf16(va, pb[kvq], acc[d], 0, 0, 0);
        }
      }
    }
    if (t < t1) {
      commit(cur ^ 1);
      __syncthreads();
      cur ^= 1;
    }
  }
  {
    const float Mf = fmaxf(mm, sk);
    const float ex = exp2f(mm - Mf);
    const float denom = ll * ex + exp2f(sk - Mf);
    const float fac = ex / denom;
    float* orow = outg + (((size_t)b * SS + qrow) * HQ + hq) * DD;
    #pragma unroll
    for (int d = 0; d < 4; ++d) {
      #pragma unroll
      for (int q4 = 0; q4 < 4; ++q4) {
        float4 o;
        o.x = acc[d][q4 * 4 + 0] * fac;
        o.y = acc[d][q4 * 4 + 1] * fac;
        o.z = acc[d][q4 * 4 + 2] * fac;
        o.w = acc[d][q4 * 4 + 3] * fac;
        *(float4*)(orow + d * 32 + q4 * 8 + 4 * hi) = o;
      }
    }
  }
}

// ---- cache path ----
__global__ void build_inv(const int* __restrict__ ids, int* __restrict__ inv,
                          int npages, int nslots) {
  const int i = threadIdx.x;
  if (i < npages) inv[i] = -1;
  __syncthreads();
  if (i < nslots) inv[ids[i]] = i;
}

__global__ void page_fill(const float* __restrict__ kg, const float* __restrict__ vg,
                          const float* __restrict__ cache_in, const int* __restrict__ inv,
                          float* __restrict__ cache) {
  const int page = blockIdx.x, half = blockIdx.y;
  const int slot = inv[page];
  float4* d4 = (float4*)cache;
  const size_t dbase = (((size_t)page * 2 + half) * 8) * 1024;
  if (slot >= 0) {
    const int b = slot >> 6, blk = slot & 63;
    const float4* s4 = (const float4*)(half ? vg : kg);
    for (int f = threadIdx.x; f < 8192; f += blockDim.x) {
      const int d = f & 31, s = (f >> 5) & 31, h = f >> 10;
      d4[dbase + (size_t)h * 1024 + s * 32 + d] =
          s4[(((size_t)b * SS + blk * 32 + s) * 8 + h) * 32 + d];
    }
  } else {
    const float4* s4 = (const float4*)cache_in;
    for (int f = threadIdx.x; f < 8192; f += blockDim.x)
      d4[dbase + f] = s4[dbase + f];
  }
}

__global__ void cache_copy(const float* __restrict__ src, float* __restrict__ dst, int n4) {
  const float4* s = (const float4*)src;
  float4* d = (float4*)dst;
  for (int i = blockIdx.x * blockDim.x + threadIdx.x; i < n4; i += gridDim.x * blockDim.x)
    d[i] = s[i];
}
__global__ void cache_scatter(const float* __restrict__ kg, const float* __restrict__ vg,
                              const int* __restrict__ ids, float* __restrict__ cache) {
  const int slot = blockIdx.x;
  const int half = blockIdx.y;
  const int b = slot >> 6, blk = slot & 63;
  const int page = ids[slot];
  const float4* s4 = (const float4*)(half ? vg : kg);
  float4* d4 = (float4*)cache;
  for (int f = threadIdx.x; f < 8192; f += blockDim.x) {
    const int d = f & 31, s = (f >> 5) & 31, h = f >> 10;
    d4[(((size_t)page * 2 + half) * 8 + h) * 1024 + s * 32 + d] =
        s4[(((size_t)b * SS + blk * 32 + s) * 8 + h) * 32 + d];
  }
}

extern "C" void kernel_launch(void* const* d_in, const int* in_sizes, int n_in,
                              void* d_out, int out_size, void* d_ws, size_t ws_size,
                              hipStream_t stream) {
  const float* q = (const float*)d_in[0];
  const float* k = (const float*)d_in[1];
  const float* v = (const float*)d_in[2];
  const float* cache_in = (const float*)d_in[3];
  const int* ids = (const int*)d_in[4];
  const float* sink = (const float*)d_in[5];
  float* out = (float*)d_out;
  float* cache_out = out + (size_t)BB * SS * HQ * DD;

  const int nslots = in_sizes[4];                       // 128
  const int npages = in_sizes[3] / (2 * HKV * 32 * DD); // 128

  const size_t imgBytes = (size_t)16 * 32 * 32768;      // 16 MB
  const size_t need = 4096 + imgBytes;
  const bool smallMaps = (npages <= 1024) && (nslots <= 1024);

  if (ws_size >= need && smallMaps) {
    int* inv = (int*)d_ws;
    char* kvimg = (char*)d_ws + 4096;
    build_inv<<<1, 1024, 0, stream>>>(ids, inv, npages, nslots);
    page_fill<<<dim3(npages, 2), 256, 0, stream>>>(k, v, cache_in, inv, cache_out);
    prep_kv<<<dim3(16 * 32, 2), 256, 0, stream>>>(k, v, kvimg);
    attn_kernel<<<512, 512, 0, stream>>>(q, sink, out, kvimg);
  } else if (ws_size >= (size_t)npages * sizeof(int) && smallMaps) {
    int* inv = (int*)d_ws;
    build_inv<<<1, 1024, 0, stream>>>(ids, inv, npages, nslots);
    page_fill<<<dim3(npages, 2), 256, 0, stream>>>(k, v, cache_in, inv, cache_out);
    attn_fallback<<<512, 512, 0, stream>>>(q, k, v, sink, out);
  } else {
    cache_copy<<<4096, 256, 0, stream>>>(cache_in, cache_out, (BB * SS * HKV * DD * 2) / 4);
    cache_scatter<<<dim3(BB * 64, 2), 256, 0, stream>>>(k, v, ids, cache_out);
    attn_fallback<<<512, 512, 0, stream>>>(q, k, v, sink, out);
  }
}